// Round 3
// baseline (299.486 us; speedup 1.0000x reference)
//
#include <hip/hip_runtime.h>

// Problem constants
#define BATCH 4
#define SEQ   2048
#define DIM   1024
#define MTOT  (BATCH * SEQ)   // 8192

typedef __bf16 bf16x8 __attribute__((ext_vector_type(8)));
typedef float  f32x4  __attribute__((ext_vector_type(4)));

// Async global->LDS, 16B per lane. LDS dest is wave-uniform base + lane*16;
// passing per-lane &lds[f*8] matches that exactly (lane order == contiguous LDS).
__device__ __forceinline__ void gl_lds16(const __bf16* g, __bf16* l) {
    __builtin_amdgcn_global_load_lds(
        (const __attribute__((address_space(1))) void*)g,
        (__attribute__((address_space(3))) void*)l,
        16, 0, 0);
}

// ---------------------------------------------------------------------------
// K0: fp32 -> bf16 conversion (inputs are fp32 per the reference; compute in
// bf16 for MFMA). Each thread converts 8 elements. n must be a multiple of 8.
__global__ __launch_bounds__(256) void cvt_kernel(
    const float* __restrict__ s, __bf16* __restrict__ d, int n)
{
    const int i = (blockIdx.x * 256 + threadIdx.x) * 8;
    if (i >= n) return;
    const float4 a = *(const float4*)(s + i);
    const float4 b = *(const float4*)(s + i + 4);
    bf16x8 o;
    o[0] = (__bf16)a.x; o[1] = (__bf16)a.y; o[2] = (__bf16)a.z; o[3] = (__bf16)a.w;
    o[4] = (__bf16)b.x; o[5] = (__bf16)b.y; o[6] = (__bf16)b.z; o[7] = (__bf16)b.w;
    *(bf16x8*)(d + i) = o;
}

// m97-style 128x128 bf16 GEMM core, C[m,n] = sum_k A[m0+m, k] * B[n0+n, k]
// (both A and B row-major with contiguous K — "B^T" layout).
// BK=32, 256 threads = 4 waves in 2x2, each wave 64x64 = 4x4 MFMA 16x16x32 tiles.
__device__ __forceinline__ void gemm_core(
    const __bf16* __restrict__ A, size_t lda,
    const __bf16* __restrict__ Bm, size_t ldb,
    int m0, int n0, int kTiles,
    __bf16* lA, __bf16* lB,
    f32x4 (&acc)[4][4])
{
    const int tid  = threadIdx.x;
    const int lane = tid & 63;
    const int wave = tid >> 6;
    const int wm = (wave >> 1) << 6;
    const int wn = (wave & 1) << 6;

#pragma unroll
    for (int i = 0; i < 4; ++i)
#pragma unroll
        for (int j = 0; j < 4; ++j)
            acc[i][j] = (f32x4){0.f, 0.f, 0.f, 0.f};

    for (int kt = 0; kt < kTiles; ++kt) {
        const int k0 = kt << 5;
        __syncthreads();
        // Stage A-tile [128][32] and B-tile [128][32], row-major, no pad.
#pragma unroll
        for (int it = 0; it < 2; ++it) {
            const int f   = tid + (it << 8);     // 8-elem group id, 0..511
            const int row = f >> 2;
            const int col = (f & 3) << 3;
            gl_lds16(A  + (size_t)(m0 + row) * lda + (size_t)(k0 + col), lA + f * 8);
            gl_lds16(Bm + (size_t)(n0 + row) * ldb + (size_t)(k0 + col), lB + f * 8);
        }
        __syncthreads();

        bf16x8 af[4], bfr[4];
#pragma unroll
        for (int i = 0; i < 4; ++i) {
            af[i]  = *(const bf16x8*)(lA + (size_t)(wm + i * 16 + (lane & 15)) * 32 + ((lane >> 4) << 3));
            bfr[i] = *(const bf16x8*)(lB + (size_t)(wn + i * 16 + (lane & 15)) * 32 + ((lane >> 4) << 3));
        }
#pragma unroll
        for (int i = 0; i < 4; ++i)
#pragma unroll
            for (int j = 0; j < 4; ++j)
                acc[i][j] = __builtin_amdgcn_mfma_f32_16x16x32_bf16(af[i], bfr[j], acc[i][j], 0, 0, 0);
    }
}

// ---------------------------------------------------------------------------
// K1: Q = x@Wq^T, K = x@Wk^T, V = x@Wv^T (V stored transposed per batch:
// Vt[b][d][s]). grid = (8, 64, 3).
__global__ __launch_bounds__(256) void qkv_kernel(
    const __bf16* __restrict__ x,
    const __bf16* __restrict__ Wq,
    const __bf16* __restrict__ Wk,
    const __bf16* __restrict__ Wv,
    __bf16* __restrict__ Q, __bf16* __restrict__ Kb, __bf16* __restrict__ Vt)
{
    __shared__ __bf16 lA[128 * 32];
    __shared__ __bf16 lB[128 * 32];
    const int n0 = blockIdx.x << 7;
    const int m0 = blockIdx.y << 7;
    const int z  = blockIdx.z;
    const __bf16* W = (z == 0) ? Wq : (z == 1) ? Wk : Wv;

    f32x4 acc[4][4];
    gemm_core(x, DIM, W, DIM, m0, n0, DIM / 32, lA, lB, acc);

    const int lane = threadIdx.x & 63;
    const int wave = threadIdx.x >> 6;
    const int wm = (wave >> 1) << 6, wn = (wave & 1) << 6;
#pragma unroll
    for (int i = 0; i < 4; ++i)
#pragma unroll
        for (int j = 0; j < 4; ++j)
#pragma unroll
            for (int r = 0; r < 4; ++r) {
                const int m = m0 + wm + i * 16 + ((lane >> 4) << 2) + r;
                const int n = n0 + wn + j * 16 + (lane & 15);
                const __bf16 vbf = (__bf16)acc[i][j][r];
                if (z == 0) {
                    Q[(size_t)m * DIM + n] = vbf;
                } else if (z == 1) {
                    Kb[(size_t)m * DIM + n] = vbf;
                } else {
                    const int b = m >> 11, ms = m & (SEQ - 1);
                    Vt[((size_t)b * DIM + n) * SEQ + ms] = vbf;
                }
            }
}

// ---------------------------------------------------------------------------
// K2: Sc[b] = Q[b]·K[b]^T * (1/32), lower-triangle blocks only. grid (16,16,4).
__global__ __launch_bounds__(256) void scores_kernel(
    const __bf16* __restrict__ Q, const __bf16* __restrict__ Kb,
    float* __restrict__ Sc)
{
    const int j = blockIdx.x;   // kv block
    const int i = blockIdx.y;   // q block
    const int b = blockIdx.z;
    if (j > i) return;

    __shared__ __bf16 lA[128 * 32];
    __shared__ __bf16 lB[128 * 32];
    const __bf16* A  = Q  + (size_t)b * SEQ * DIM;
    const __bf16* Bm = Kb + (size_t)b * SEQ * DIM;

    f32x4 acc[4][4];
    gemm_core(A, DIM, Bm, DIM, i << 7, j << 7, DIM / 32, lA, lB, acc);

    float* out = Sc + (size_t)b * SEQ * SEQ;
    const int lane = threadIdx.x & 63;
    const int wave = threadIdx.x >> 6;
    const int wm = (wave >> 1) << 6, wn = (wave & 1) << 6;
#pragma unroll
    for (int ii = 0; ii < 4; ++ii)
#pragma unroll
        for (int jj = 0; jj < 4; ++jj)
#pragma unroll
            for (int r = 0; r < 4; ++r) {
                const int m = (i << 7) + wm + ii * 16 + ((lane >> 4) << 2) + r;
                const int n = (j << 7) + wn + jj * 16 + (lane & 15);
                out[(size_t)m * SEQ + n] = acc[ii][jj][r] * 0.03125f;  // 1/sqrt(1024)
            }
}

// ---------------------------------------------------------------------------
// K3: causal row softmax; writes bf16 P in place over the fp32 row (same byte
// offsets -> P row stride = 2*SEQ bf16 elems). Zeros fill up to the 128-tile
// boundary so PV diagonal tiles read valid zeros. grid = 8192 blocks of 256.
__global__ __launch_bounds__(256) void softmax_kernel(float* __restrict__ Sc)
{
    const int rg = blockIdx.x;
    const int b  = rg >> 11;
    const int r  = rg & (SEQ - 1);
    float* row = Sc + ((size_t)b * SEQ + r) * SEQ;
    __bf16* prow = (__bf16*)row;

    const int tid  = threadIdx.x;
    const int lane = tid & 63;
    const int wv   = tid >> 6;
    const int width = ((r >> 7) + 1) << 7;   // tile-rounded valid width

    float v[8];
    float mx = -1e30f;
#pragma unroll
    for (int k = 0; k < 8; ++k) {
        const int c = tid + (k << 8);
        v[k] = (c <= r) ? row[c] : -1e30f;
        mx = fmaxf(mx, v[k]);
    }
#pragma unroll
    for (int off = 32; off > 0; off >>= 1)
        mx = fmaxf(mx, __shfl_xor(mx, off));

    __shared__ float red[4];
    if (lane == 0) red[wv] = mx;
    __syncthreads();
    mx = fmaxf(fmaxf(red[0], red[1]), fmaxf(red[2], red[3]));

    float s = 0.f;
#pragma unroll
    for (int k = 0; k < 8; ++k) {
        const int c = tid + (k << 8);
        v[k] = (c <= r) ? __expf(v[k] - mx) : 0.f;
        s += v[k];
    }
#pragma unroll
    for (int off = 32; off > 0; off >>= 1)
        s += __shfl_xor(s, off);
    __syncthreads();             // red reuse
    if (lane == 0) red[wv] = s;
    __syncthreads();
    s = red[0] + red[1] + red[2] + red[3];
    const float inv = 1.f / s;

#pragma unroll
    for (int k = 0; k < 8; ++k) {
        const int c = tid + (k << 8);
        if (c < width) prow[c] = (__bf16)(v[k] * inv);
    }
}

// ---------------------------------------------------------------------------
// K4: O[b] = P[b] @ V[b]  (A = P bf16, lda = 2*SEQ; B = Vt). k-tiles only up
// to the causal diagonal. Output is FP32 (reference output dtype). grid (8,16,4).
__global__ __launch_bounds__(256) void pv_kernel(
    const __bf16* __restrict__ P, const __bf16* __restrict__ Vt,
    float* __restrict__ out)
{
    const int x = blockIdx.x;   // feature block
    const int i = blockIdx.y;   // q block
    const int b = blockIdx.z;

    __shared__ __bf16 lA[128 * 32];
    __shared__ __bf16 lB[128 * 32];
    const __bf16* A  = P  + (size_t)b * SEQ * SEQ * 2;   // bf16 view of fp32 rows
    const __bf16* Bm = Vt + (size_t)b * DIM * SEQ;

    f32x4 acc[4][4];
    gemm_core(A, 2 * SEQ, Bm, SEQ, i << 7, x << 7, (i + 1) * 4, lA, lB, acc);

    const int lane = threadIdx.x & 63;
    const int wave = threadIdx.x >> 6;
    const int wm = (wave >> 1) << 6, wn = (wave & 1) << 6;
#pragma unroll
    for (int ii = 0; ii < 4; ++ii)
#pragma unroll
        for (int jj = 0; jj < 4; ++jj)
#pragma unroll
            for (int r = 0; r < 4; ++r) {
                const int m = (i << 7) + wm + ii * 16 + ((lane >> 4) << 2) + r;
                const int n = (x << 7) + wn + jj * 16 + (lane & 15);
                out[((size_t)b * SEQ + m) * DIM + n] = acc[ii][jj][r];
            }
}

// ---------------------------------------------------------------------------
extern "C" void kernel_launch(void* const* d_in, const int* in_sizes, int n_in,
                              void* d_out, int out_size, void* d_ws, size_t ws_size,
                              hipStream_t stream) {
    const float* x  = (const float*)d_in[0];   // fp32 per reference
    const float* Wq = (const float*)d_in[1];
    const float* Wk = (const float*)d_in[2];
    const float* Wv = (const float*)d_in[3];
    float* out = (float*)d_out;                // fp32 output (reference dtype)

    char* ws = (char*)d_ws;
    __bf16* Q  = (__bf16*)(ws);                       // 16 MB
    __bf16* Kb = (__bf16*)(ws + (16ull << 20));       // 16 MB
    __bf16* Vt = (__bf16*)(ws + (32ull << 20));       // 16 MB
    float*  Sc = (float*) (ws + (48ull << 20));       // 64 MB (P in place)
    // bf16 copies of the inputs live INSIDE the Sc region: they are dead
    // after qkv_kernel, and Sc is first written by scores_kernel (later).
    __bf16* xb  = (__bf16*)(ws + (48ull << 20));      // 16 MB (aliases Sc head)
    __bf16* Wqb = (__bf16*)(ws + (64ull << 20));      // 2 MB
    __bf16* Wkb = (__bf16*)(ws + (66ull << 20));      // 2 MB
    __bf16* Wvb = (__bf16*)(ws + (68ull << 20));      // 2 MB

    const int nx = BATCH * SEQ * DIM;   // 8388608
    const int nw = DIM * DIM;           // 1048576
    cvt_kernel<<<dim3(nx / (256 * 8)), 256, 0, stream>>>(x,  xb,  nx);
    cvt_kernel<<<dim3(nw / (256 * 8)), 256, 0, stream>>>(Wq, Wqb, nw);
    cvt_kernel<<<dim3(nw / (256 * 8)), 256, 0, stream>>>(Wk, Wkb, nw);
    cvt_kernel<<<dim3(nw / (256 * 8)), 256, 0, stream>>>(Wv, Wvb, nw);

    qkv_kernel    <<<dim3(8, 64, 3),  256, 0, stream>>>(xb, Wqb, Wkb, Wvb, Q, Kb, Vt);
    scores_kernel <<<dim3(16, 16, 4), 256, 0, stream>>>(Q, Kb, Sc);
    softmax_kernel<<<dim3(MTOT),      256, 0, stream>>>(Sc);
    pv_kernel     <<<dim3(8, 16, 4),  256, 0, stream>>>((const __bf16*)Sc, Vt, out);
}

// Round 4
// 285.254 us; speedup vs baseline: 1.0499x; 1.0499x over previous
//
#include <hip/hip_runtime.h>

// Problem constants
#define BATCH 4
#define SEQ   2048
#define DIM   1024
#define MTOT  (BATCH * SEQ)   // 8192
#define BK    64              // k-tile depth (BK=64: 32 MFMA per barrier pair)

typedef __bf16 bf16x8 __attribute__((ext_vector_type(8)));
typedef float  f32x4  __attribute__((ext_vector_type(4)));

// Async global->LDS, 16B per lane. LDS dest is wave-uniform base + lane*16;
// per-lane &lds[f*8] matches (lane order == contiguous LDS).
__device__ __forceinline__ void gl_lds16(const __bf16* g, __bf16* l) {
    __builtin_amdgcn_global_load_lds(
        (const __attribute__((address_space(1))) void*)g,
        (__attribute__((address_space(3))) void*)l,
        16, 0, 0);
}

// ---------------------------------------------------------------------------
// K0a: fp32 -> bf16 for x. K0b: all three weights in one launch (z picks W).
__global__ __launch_bounds__(256) void cvt_kernel(
    const float* __restrict__ s, __bf16* __restrict__ d, int n)
{
    const int i = (blockIdx.x * 256 + threadIdx.x) * 8;
    if (i >= n) return;
    const float4 a = *(const float4*)(s + i);
    const float4 b = *(const float4*)(s + i + 4);
    bf16x8 o;
    o[0] = (__bf16)a.x; o[1] = (__bf16)a.y; o[2] = (__bf16)a.z; o[3] = (__bf16)a.w;
    o[4] = (__bf16)b.x; o[5] = (__bf16)b.y; o[6] = (__bf16)b.z; o[7] = (__bf16)b.w;
    *(bf16x8*)(d + i) = o;
}

__global__ __launch_bounds__(256) void cvt3_kernel(
    const float* __restrict__ w0, const float* __restrict__ w1,
    const float* __restrict__ w2, __bf16* __restrict__ d0,
    __bf16* __restrict__ d1, __bf16* __restrict__ d2)
{
    const int z = blockIdx.y;
    const float* s = (z == 0) ? w0 : (z == 1) ? w1 : w2;
    __bf16* d = (z == 0) ? d0 : (z == 1) ? d1 : d2;
    const int i = (blockIdx.x * 256 + threadIdx.x) * 8;
    const float4 a = *(const float4*)(s + i);
    const float4 b = *(const float4*)(s + i + 4);
    bf16x8 o;
    o[0] = (__bf16)a.x; o[1] = (__bf16)a.y; o[2] = (__bf16)a.z; o[3] = (__bf16)a.w;
    o[4] = (__bf16)b.x; o[5] = (__bf16)b.y; o[6] = (__bf16)b.z; o[7] = (__bf16)b.w;
    *(bf16x8*)(d + i) = o;
}

// ---------------------------------------------------------------------------
// 128x128 bf16 GEMM core, C[m,n] = sum_k A[m0+m,k] * B[n0+n,k] (both row-major,
// contiguous K). BK=64: per k-tile stage 2x16KB, then 2 sub-steps x 16 MFMA.
// 256 threads = 4 waves 2x2, each wave 64x64 = 4x4 16x16x32 tiles.
__device__ __forceinline__ void gemm_core(
    const __bf16* __restrict__ A, size_t lda,
    const __bf16* __restrict__ Bm, size_t ldb,
    int m0, int n0, int kTiles,
    __bf16* lA, __bf16* lB,
    f32x4 (&acc)[4][4])
{
    const int tid  = threadIdx.x;
    const int lane = tid & 63;
    const int wave = tid >> 6;
    const int wm = (wave >> 1) << 6;
    const int wn = (wave & 1) << 6;

#pragma unroll
    for (int i = 0; i < 4; ++i)
#pragma unroll
        for (int j = 0; j < 4; ++j)
            acc[i][j] = (f32x4){0.f, 0.f, 0.f, 0.f};

    for (int kt = 0; kt < kTiles; ++kt) {
        const int k0 = kt * BK;
        __syncthreads();
        // Stage A-tile [128][64] and B-tile [128][64], row-major, no pad.
#pragma unroll
        for (int it = 0; it < 4; ++it) {
            const int f   = tid + (it << 8);     // 8-elem group id, 0..1023
            const int row = f >> 3;
            const int col = (f & 7) << 3;
            gl_lds16(A  + (size_t)(m0 + row) * lda + (size_t)(k0 + col), lA + f * 8);
            gl_lds16(Bm + (size_t)(n0 + row) * ldb + (size_t)(k0 + col), lB + f * 8);
        }
        __syncthreads();

#pragma unroll
        for (int s = 0; s < 2; ++s) {
            bf16x8 af[4], bfr[4];
#pragma unroll
            for (int i = 0; i < 4; ++i) {
                af[i]  = *(const bf16x8*)(lA + (size_t)(wm + i * 16 + (lane & 15)) * BK + (s << 5) + ((lane >> 4) << 3));
                bfr[i] = *(const bf16x8*)(lB + (size_t)(wn + i * 16 + (lane & 15)) * BK + (s << 5) + ((lane >> 4) << 3));
            }
#pragma unroll
            for (int i = 0; i < 4; ++i)
#pragma unroll
                for (int j = 0; j < 4; ++j)
                    acc[i][j] = __builtin_amdgcn_mfma_f32_16x16x32_bf16(af[i], bfr[j], acc[i][j], 0, 0, 0);
        }
    }
}

// Epilogue helper: C-tile (bf16) -> LDS scratch (32 KB, reuses staging bufs)
// -> coalesced bf16x8 global row stores. transpose=false: scratch[m][n],
// row-major out rows of length ldo at `dst + (r0+row)*ldo + c0`.
__device__ __forceinline__ void store_tile_bf16(
    f32x4 (&acc)[4][4], __bf16* scratch, bool transpose,
    __bf16* dst, size_t ldo, size_t r0, size_t c0)
{
    const int tid  = threadIdx.x;
    const int lane = tid & 63;
    const int wave = tid >> 6;
    const int wm = (wave >> 1) << 6, wn = (wave & 1) << 6;

    __syncthreads();   // staging buffers now dead; safe to reuse
#pragma unroll
    for (int i = 0; i < 4; ++i)
#pragma unroll
        for (int j = 0; j < 4; ++j)
#pragma unroll
            for (int r = 0; r < 4; ++r) {
                const int ml = wm + i * 16 + ((lane >> 4) << 2) + r;
                const int nl = wn + j * 16 + (lane & 15);
                if (transpose) scratch[nl * 128 + ml] = (__bf16)acc[i][j][r];
                else           scratch[ml * 128 + nl] = (__bf16)acc[i][j][r];
            }
    __syncthreads();
#pragma unroll
    for (int it = 0; it < 8; ++it) {
        const int g   = tid + (it << 8);    // 0..2047
        const int row = g >> 4;
        const int col = (g & 15) << 3;
        *(bf16x8*)(dst + (r0 + row) * ldo + c0 + col) = *(const bf16x8*)(scratch + row * 128 + col);
    }
}

// ---------------------------------------------------------------------------
// K1: Q = x@Wq^T, K = x@Wk^T, V = x@Wv^T (V stored transposed per batch:
// Vt[b][d][s]). grid = (8, 64, 3).
__global__ __launch_bounds__(256) void qkv_kernel(
    const __bf16* __restrict__ x,
    const __bf16* __restrict__ Wq,
    const __bf16* __restrict__ Wk,
    const __bf16* __restrict__ Wv,
    __bf16* __restrict__ Q, __bf16* __restrict__ Kb, __bf16* __restrict__ Vt)
{
    __shared__ __bf16 smem[2 * 128 * BK];     // 32 KB: staging, then C scratch
    __bf16* lA = smem;
    __bf16* lB = smem + 128 * BK;
    const int n0 = blockIdx.x << 7;
    const int m0 = blockIdx.y << 7;
    const int z  = blockIdx.z;
    const __bf16* W = (z == 0) ? Wq : (z == 1) ? Wk : Wv;

    f32x4 acc[4][4];
    gemm_core(x, DIM, W, DIM, m0, n0, DIM / BK, lA, lB, acc);

    if (z == 0) {
        store_tile_bf16(acc, smem, false, Q,  DIM, m0, n0);
    } else if (z == 1) {
        store_tile_bf16(acc, smem, false, Kb, DIM, m0, n0);
    } else {
        // Vt[b][d][s]: rows are features (n), cols are seq (m) -> transpose.
        const size_t b = (size_t)(m0 >> 11), ms0 = (size_t)(m0 & (SEQ - 1));
        store_tile_bf16(acc, smem, true, Vt + b * DIM * SEQ, SEQ, n0, ms0);
    }
}

// ---------------------------------------------------------------------------
// K2: Sc[b] = Q[b]·K[b]^T * (1/32), lower-triangle blocks only. grid (16,16,4).
__global__ __launch_bounds__(256) void scores_kernel(
    const __bf16* __restrict__ Q, const __bf16* __restrict__ Kb,
    float* __restrict__ Sc)
{
    const int j = blockIdx.x;   // kv block
    const int i = blockIdx.y;   // q block
    const int b = blockIdx.z;
    if (j > i) return;

    __shared__ __bf16 smem[2 * 128 * BK];
    __bf16* lA = smem;
    __bf16* lB = smem + 128 * BK;
    const __bf16* A  = Q  + (size_t)b * SEQ * DIM;
    const __bf16* Bm = Kb + (size_t)b * SEQ * DIM;

    f32x4 acc[4][4];
    gemm_core(A, DIM, Bm, DIM, i << 7, j << 7, DIM / BK, lA, lB, acc);

    float* out = Sc + (size_t)b * SEQ * SEQ;
    const int lane = threadIdx.x & 63;
    const int wave = threadIdx.x >> 6;
    const int wm = (wave >> 1) << 6, wn = (wave & 1) << 6;
#pragma unroll
    for (int ii = 0; ii < 4; ++ii)
#pragma unroll
        for (int jj = 0; jj < 4; ++jj)
#pragma unroll
            for (int r = 0; r < 4; ++r) {
                const int m = (i << 7) + wm + ii * 16 + ((lane >> 4) << 2) + r;
                const int n = (j << 7) + wn + jj * 16 + (lane & 15);
                out[(size_t)m * SEQ + n] = acc[ii][jj][r] * 0.03125f;  // 1/sqrt(1024)
            }
}

// ---------------------------------------------------------------------------
// K3: causal row softmax; writes bf16 P in place over the fp32 row (same byte
// offsets -> P row stride = 2*SEQ bf16 elems). Zeros fill up to the 128-tile
// boundary so PV diagonal tiles read valid zeros. grid = 8192 blocks of 256.
__global__ __launch_bounds__(256) void softmax_kernel(float* __restrict__ Sc)
{
    const int rg = blockIdx.x;
    const int b  = rg >> 11;
    const int r  = rg & (SEQ - 1);
    float* row = Sc + ((size_t)b * SEQ + r) * SEQ;
    __bf16* prow = (__bf16*)row;

    const int tid  = threadIdx.x;
    const int lane = tid & 63;
    const int wv   = tid >> 6;
    const int width = ((r >> 7) + 1) << 7;   // tile-rounded valid width

    float v[8];
    float mx = -1e30f;
#pragma unroll
    for (int k = 0; k < 8; ++k) {
        const int c = tid + (k << 8);
        v[k] = (c <= r) ? row[c] : -1e30f;
        mx = fmaxf(mx, v[k]);
    }
#pragma unroll
    for (int off = 32; off > 0; off >>= 1)
        mx = fmaxf(mx, __shfl_xor(mx, off));

    __shared__ float red[4];
    if (lane == 0) red[wv] = mx;
    __syncthreads();
    mx = fmaxf(fmaxf(red[0], red[1]), fmaxf(red[2], red[3]));

    float s = 0.f;
#pragma unroll
    for (int k = 0; k < 8; ++k) {
        const int c = tid + (k << 8);
        v[k] = (c <= r) ? __expf(v[k] - mx) : 0.f;
        s += v[k];
    }
#pragma unroll
    for (int off = 32; off > 0; off >>= 1)
        s += __shfl_xor(s, off);
    __syncthreads();             // red reuse
    if (lane == 0) red[wv] = s;
    __syncthreads();
    s = red[0] + red[1] + red[2] + red[3];
    const float inv = 1.f / s;

#pragma unroll
    for (int k = 0; k < 8; ++k) {
        const int c = tid + (k << 8);
        if (c < width) prow[c] = (__bf16)(v[k] * inv);
    }
}

// ---------------------------------------------------------------------------
// K4: O[b] = P[b] @ V[b]  (A = P bf16, lda = 2*SEQ; B = Vt). k-tiles only up
// to the causal diagonal. Output fp32 (reference dtype). grid (8,16,4).
__global__ __launch_bounds__(256) void pv_kernel(
    const __bf16* __restrict__ P, const __bf16* __restrict__ Vt,
    float* __restrict__ out)
{
    const int x = blockIdx.x;   // feature block
    const int i = blockIdx.y;   // q block
    const int b = blockIdx.z;

    __shared__ __bf16 smem[2 * 128 * BK];
    __bf16* lA = smem;
    __bf16* lB = smem + 128 * BK;
    const __bf16* A  = P  + (size_t)b * SEQ * SEQ * 2;   // bf16 view of fp32 rows
    const __bf16* Bm = Vt + (size_t)b * DIM * SEQ;

    f32x4 acc[4][4];
    gemm_core(A, 2 * SEQ, Bm, SEQ, i << 7, x << 7, (i + 1) * (128 / BK), lA, lB, acc);

    const int lane = threadIdx.x & 63;
    const int wave = threadIdx.x >> 6;
    const int wm = (wave >> 1) << 6, wn = (wave & 1) << 6;
#pragma unroll
    for (int ii = 0; ii < 4; ++ii)
#pragma unroll
        for (int jj = 0; jj < 4; ++jj)
#pragma unroll
            for (int r = 0; r < 4; ++r) {
                const int m = (i << 7) + wm + ii * 16 + ((lane >> 4) << 2) + r;
                const int n = (x << 7) + wn + jj * 16 + (lane & 15);
                out[((size_t)b * SEQ + m) * DIM + n] = acc[ii][jj][r];
            }
}

// ---------------------------------------------------------------------------
extern "C" void kernel_launch(void* const* d_in, const int* in_sizes, int n_in,
                              void* d_out, int out_size, void* d_ws, size_t ws_size,
                              hipStream_t stream) {
    const float* x  = (const float*)d_in[0];   // fp32 per reference
    const float* Wq = (const float*)d_in[1];
    const float* Wk = (const float*)d_in[2];
    const float* Wv = (const float*)d_in[3];
    float* out = (float*)d_out;                // fp32 output (reference dtype)

    char* ws = (char*)d_ws;
    __bf16* Q  = (__bf16*)(ws);                       // 16 MB
    __bf16* Kb = (__bf16*)(ws + (16ull << 20));       // 16 MB
    __bf16* Vt = (__bf16*)(ws + (32ull << 20));       // 16 MB
    float*  Sc = (float*) (ws + (48ull << 20));       // 64 MB (P in place)
    // bf16 copies of the inputs live INSIDE the Sc region: they are dead
    // after qkv_kernel, and Sc is first written by scores_kernel (later).
    __bf16* xb  = (__bf16*)(ws + (48ull << 20));      // 16 MB (aliases Sc head)
    __bf16* Wqb = (__bf16*)(ws + (64ull << 20));      // 2 MB
    __bf16* Wkb = (__bf16*)(ws + (66ull << 20));      // 2 MB
    __bf16* Wvb = (__bf16*)(ws + (68ull << 20));      // 2 MB

    const int nx = BATCH * SEQ * DIM;   // 8388608
    const int nw = DIM * DIM;           // 1048576
    cvt_kernel <<<dim3(nx / (256 * 8)),    256, 0, stream>>>(x, xb, nx);
    cvt3_kernel<<<dim3(nw / (256 * 8), 3), 256, 0, stream>>>(Wq, Wk, Wv, Wqb, Wkb, Wvb);

    qkv_kernel    <<<dim3(8, 64, 3),  256, 0, stream>>>(xb, Wqb, Wkb, Wvb, Q, Kb, Vt);
    scores_kernel <<<dim3(16, 16, 4), 256, 0, stream>>>(Q, Kb, Sc);
    softmax_kernel<<<dim3(MTOT),      256, 0, stream>>>(Sc);
    pv_kernel     <<<dim3(8, 16, 4),  256, 0, stream>>>((const __bf16*)Sc, Vt, out);
}